// Round 1
// baseline (286.794 us; speedup 1.0000x reference)
//
#include <hip/hip_runtime.h>
#include <stdint.h>

// SpatialHyperedgeMP: out = ((inc + head) @ cur) / rowsum(inc + head)
//   head_ij = (inc_ij > 0) / sqrt(cnt_i),  cnt_i = #positives in row i
//
// Kernel plan:
//   1) stats:  per-row fp64 sum + positive count -> invs[i]=1/sqrt(cnt), rdeg[i]=1/(s1+sqrt(cnt))
//   2) bprep:  cur fp32 -> bf16, transposed into MFMA-chunk layout in ws
//   3) gemm:   bf16 MFMA 16x16x32, BM=64 BN=256 BK=64, fused A transform, epilogue * rdeg
//
// ws usage: 32KB invs + 32KB rdeg + 8MB B chunks = 8454144 bytes total.

#define NROWS 8192
#define DDIM  512

typedef float f32x4 __attribute__((ext_vector_type(4)));
typedef short s16x8 __attribute__((ext_vector_type(8)));

__device__ __forceinline__ unsigned short f2bf(float f) {
  union { float f; unsigned int u; } c; c.f = f;
  unsigned int u = c.u;
  unsigned int r = u + 0x7FFFu + ((u >> 16) & 1u);
  return (unsigned short)(r >> 16);
}

// ---------------- kernel 1: row stats ----------------
__global__ __launch_bounds__(256) void stats_kernel(const float* __restrict__ inc,
                                                    float* __restrict__ invs,
                                                    float* __restrict__ rdeg) {
  int row = blockIdx.x;
  int tid = threadIdx.x;
  const float4* p = (const float4*)(inc + (size_t)row * NROWS);
  double s = 0.0;
  int c = 0;
#pragma unroll
  for (int i = 0; i < 8; ++i) {
    float4 v = p[i * 256 + tid];
    s += (double)v.x + (double)v.y + (double)v.z + (double)v.w;
    c += (v.x > 0.f) + (v.y > 0.f) + (v.z > 0.f) + (v.w > 0.f);
  }
  for (int off = 32; off > 0; off >>= 1) {
    s += __shfl_down(s, off);
    c += __shfl_down(c, off);
  }
  __shared__ double sw[4];
  __shared__ int cw[4];
  int lane = tid & 63, wv = tid >> 6;
  if (lane == 0) { sw[wv] = s; cw[wv] = c; }
  __syncthreads();
  if (tid == 0) {
    double S = sw[0] + sw[1] + sw[2] + sw[3];
    int C = cw[0] + cw[1] + cw[2] + cw[3];
    double sq = sqrt((double)C);
    invs[row] = (C > 0) ? (float)(1.0 / sq) : 0.0f;
    rdeg[row] = (float)(1.0 / (S + sq));
  }
}

// ---------------- kernel 2: B prep (cur -> bf16 chunked-transposed) ----------------
// chunk layout: for nt(2) x kt(128): 32KB chunk = [kg=8][nn=256][e=8] bf16
//   element (k, n): chunk(n>>8, k>>6), kg=(k&63)>>3, nn=n&255, e=k&7
__global__ __launch_bounds__(256) void bprep_kernel(const float* __restrict__ cur,
                                                    unsigned char* __restrict__ bws) {
  int idx = blockIdx.x * 256 + threadIdx.x;  // 0..524287
  int n = idx & 511;
  int kg9 = idx >> 9;  // 0..1023
  int kt = kg9 >> 3;
  int kg = kg9 & 7;
  int k0 = kt * 64 + kg * 8;
  union { unsigned short h[8]; uint4 q; } u;
#pragma unroll
  for (int e = 0; e < 8; ++e)
    u.h[e] = f2bf(cur[(size_t)(k0 + e) * DDIM + n]);
  int nt = n >> 8, nn = n & 255;
  size_t off = ((size_t)(nt * 128 + kt) << 15) + ((size_t)kg << 12) + ((size_t)nn << 4);
  *(uint4*)(bws + off) = u.q;
}

// ---------------- kernel 3: GEMM ----------------
// BM=64 BN=256 BK=64, 256 threads = 4 waves, wave tile 64x64.
// A LDS chunk layout: [kg=8][m=64][e=8] bf16 (8KB); B LDS: one 32KB chunk.
__global__ __launch_bounds__(256) void gemm_kernel(const float* __restrict__ inc,
                                                   const unsigned char* __restrict__ bws,
                                                   const float* __restrict__ invs,
                                                   const float* __restrict__ rdeg,
                                                   float* __restrict__ out) {
  __shared__ __align__(16) unsigned char smem[32768 + 8192 + 512];
  unsigned char* bTile = smem;
  unsigned char* aTile = smem + 32768;
  float* invsS = (float*)(smem + 32768 + 8192);
  float* rdegS = invsS + 64;

  int tid = threadIdx.x;
  int lane = tid & 63;
  int wv = tid >> 6;
  int nt = blockIdx.x;  // 0..1  (fastest -> column-tile partners adjacent for L3 reuse of A)
  int mt = blockIdx.y;  // 0..127
  int brow = mt * 64;
  int bcol = nt * 256;

  if (tid < 64) invsS[tid] = invs[brow + tid];
  else if (tid < 128) rdegS[tid - 64] = rdeg[brow + tid - 64];
  __syncthreads();

  // A staging assignment: 4 float4 per thread per K-step
  int smA[4], slotA[4];
  const float4* gA[4];
  float invrA[4];
#pragma unroll
  for (int i = 0; i < 4; ++i) {
    int f = i * 256 + tid;
    int sm = f >> 4, slot = f & 15;  // row-in-tile, float4-slot (k = slot*4..slot*4+3)
    smA[i] = sm; slotA[i] = slot;
    gA[i] = (const float4*)(inc + (size_t)(brow + sm) * NROWS) + slot;
    invrA[i] = invsS[sm];
  }

  const unsigned char* gB = bws + ((size_t)(nt * 128) << 15);
  int gOffLane = (wv << 10) + (lane << 4);
  int ldsWave = (wv << 10);

  // frag LDS byte offsets (fixed across K since single buffer)
  int aOff[2][4], bOff[2][4];
#pragma unroll
  for (int kh = 0; kh < 2; ++kh) {
    int kg = kh * 4 + (lane >> 4);
#pragma unroll
    for (int g = 0; g < 4; ++g) {
      aOff[kh][g] = (kg << 10) + ((g * 16 + (lane & 15)) << 4);
      bOff[kh][g] = (kg << 12) + ((wv * 64 + g * 16 + (lane & 15)) << 4);
    }
  }

  f32x4 acc[4][4];
#pragma unroll
  for (int a = 0; a < 4; ++a)
#pragma unroll
    for (int b = 0; b < 4; ++b)
      acc[a][b] = (f32x4){0.f, 0.f, 0.f, 0.f};

  for (int kt = 0; kt < 128; ++kt) {
    __syncthreads();  // previous tile's reads complete
    // ---- B stage: async global -> LDS, 8 sweeps x (4 waves x 1KB) ----
    const unsigned char* gBk = gB + ((size_t)kt << 15);
#pragma unroll
    for (int s = 0; s < 8; ++s) {
      __builtin_amdgcn_global_load_lds(
          (const __attribute__((address_space(1))) unsigned int*)(gBk + (s << 12) + gOffLane),
          (__attribute__((address_space(3))) unsigned int*)(bTile + (s << 12) + ldsWave),
          16, 0, 0);
    }
    // ---- A stage: fp32 load + fused head transform -> bf16 -> LDS ----
#pragma unroll
    for (int i = 0; i < 4; ++i) {
      float4 v = gA[i][kt * 16];
      float ir = invrA[i];
      unsigned long long pk =
          (unsigned long long)f2bf(v.x + (v.x > 0.f ? ir : 0.f)) |
          ((unsigned long long)f2bf(v.y + (v.y > 0.f ? ir : 0.f)) << 16) |
          ((unsigned long long)f2bf(v.z + (v.z > 0.f ? ir : 0.f)) << 32) |
          ((unsigned long long)f2bf(v.w + (v.w > 0.f ? ir : 0.f)) << 48);
      *(unsigned long long*)(aTile + ((slotA[i] >> 1) << 10) + (smA[i] << 4) +
                             ((slotA[i] & 1) << 3)) = pk;
    }
    __syncthreads();  // staging complete (compiler drains vmcnt/lgkm before barrier)
    // ---- compute: 32 MFMA / wave ----
#pragma unroll
    for (int kh = 0; kh < 2; ++kh) {
      s16x8 af[4], bf[4];
#pragma unroll
      for (int g = 0; g < 4; ++g) af[g] = *(const s16x8*)(aTile + aOff[kh][g]);
#pragma unroll
      for (int g = 0; g < 4; ++g) bf[g] = *(const s16x8*)(bTile + bOff[kh][g]);
#pragma unroll
      for (int rg = 0; rg < 4; ++rg)
#pragma unroll
        for (int cg = 0; cg < 4; ++cg)
          acc[rg][cg] = __builtin_amdgcn_mfma_f32_16x16x32_bf16(af[rg], bf[cg],
                                                                acc[rg][cg], 0, 0, 0);
    }
  }

  // ---- epilogue: * rdeg, store fp32 ----
#pragma unroll
  for (int rg = 0; rg < 4; ++rg) {
    int rb = rg * 16 + ((lane >> 4) << 2);
#pragma unroll
    for (int cg = 0; cg < 4; ++cg) {
      int col = bcol + wv * 64 + cg * 16 + (lane & 15);
#pragma unroll
      for (int r = 0; r < 4; ++r) {
        int rl = rb + r;
        out[(size_t)(brow + rl) * DDIM + col] = acc[rg][cg][r] * rdegS[rl];
      }
    }
  }
}

extern "C" void kernel_launch(void* const* d_in, const int* in_sizes, int n_in,
                              void* d_out, int out_size, void* d_ws, size_t ws_size,
                              hipStream_t stream) {
  const float* cur = (const float*)d_in[0];          // [8192, 512] fp32
  const float* incm = (const float*)d_in[1];         // [8192, 8192] fp32
  float* out = (float*)d_out;                        // [8192, 512] fp32
  unsigned char* ws = (unsigned char*)d_ws;
  float* invs = (float*)ws;                          // 32KB
  float* rdeg = (float*)(ws + 32768);                // 32KB
  unsigned char* bws = ws + 65536;                   // 8MB B chunks

  hipLaunchKernelGGL(stats_kernel, dim3(NROWS), dim3(256), 0, stream, incm, invs, rdeg);
  hipLaunchKernelGGL(bprep_kernel, dim3((NROWS / 64) * 8 * DDIM / 256), dim3(256), 0, stream,
                     cur, bws);
  hipLaunchKernelGGL(gemm_kernel, dim3(2, 128), dim3(256), 0, stream, incm, bws, invs, rdeg, out);
}

// Round 2
// 203.038 us; speedup vs baseline: 1.4125x; 1.4125x over previous
//
#include <hip/hip_runtime.h>
#include <stdint.h>

// SpatialHyperedgeMP: out = ((inc + head) @ cur) / rowsum(inc + head)
//   head_ij = (inc_ij > 0) / sqrt(cnt_i),  cnt_i = #positives in row i
//
// Kernels:
//   1) stats:  per-row fp64 sum + positive count -> invs[i]=1/sqrt(cnt), rdeg[i]=1/(s1+sqrt(cnt))
//   2) bprep:  cur fp32 -> bf16, transposed into MFMA-chunk layout in ws
//   3) gemm:   bf16 MFMA 16x16x32, BM=64 BN=256 BK=64, 512 thr (8 waves),
//              double-buffered LDS + async A-split (T14): issue next-tile loads
//              before MFMA, transform+ds_write after MFMA, 1 barrier/tile.
//
// ws usage: 32KB invs + 32KB rdeg + 8MB B chunks.

#define NROWS 8192
#define DDIM  512

typedef float f32x4 __attribute__((ext_vector_type(4)));
typedef short s16x8 __attribute__((ext_vector_type(8)));

__device__ __forceinline__ unsigned short f2bf(float f) {
  union { float f; unsigned int u; } c; c.f = f;
  unsigned int u = c.u;
  unsigned int r = u + 0x7FFFu + ((u >> 16) & 1u);
  return (unsigned short)(r >> 16);
}

// ---------------- kernel 1: row stats ----------------
__global__ __launch_bounds__(256) void stats_kernel(const float* __restrict__ inc,
                                                    float* __restrict__ invs,
                                                    float* __restrict__ rdeg) {
  int row = blockIdx.x;
  int tid = threadIdx.x;
  const float4* p = (const float4*)(inc + (size_t)row * NROWS);
  double s = 0.0;
  int c = 0;
#pragma unroll
  for (int i = 0; i < 8; ++i) {
    float4 v = p[i * 256 + tid];
    s += (double)v.x + (double)v.y + (double)v.z + (double)v.w;
    c += (v.x > 0.f) + (v.y > 0.f) + (v.z > 0.f) + (v.w > 0.f);
  }
  for (int off = 32; off > 0; off >>= 1) {
    s += __shfl_down(s, off);
    c += __shfl_down(c, off);
  }
  __shared__ double sw[4];
  __shared__ int cw[4];
  int lane = tid & 63, wv = tid >> 6;
  if (lane == 0) { sw[wv] = s; cw[wv] = c; }
  __syncthreads();
  if (tid == 0) {
    double S = sw[0] + sw[1] + sw[2] + sw[3];
    int C = cw[0] + cw[1] + cw[2] + cw[3];
    double sq = sqrt((double)C);
    invs[row] = (C > 0) ? (float)(1.0 / sq) : 0.0f;
    rdeg[row] = (float)(1.0 / (S + sq));
  }
}

// ---------------- kernel 2: B prep (cur -> bf16 chunked-transposed) ----------------
// chunk layout: for nt(2) x kt(128): 32KB chunk = [kg=8][nn=256][e=8] bf16
__global__ __launch_bounds__(256) void bprep_kernel(const float* __restrict__ cur,
                                                    unsigned char* __restrict__ bws) {
  int idx = blockIdx.x * 256 + threadIdx.x;  // 0..524287
  int n = idx & 511;
  int kg9 = idx >> 9;  // 0..1023
  int kt = kg9 >> 3;
  int kg = kg9 & 7;
  int k0 = kt * 64 + kg * 8;
  union { unsigned short h[8]; uint4 q; } u;
#pragma unroll
  for (int e = 0; e < 8; ++e)
    u.h[e] = f2bf(cur[(size_t)(k0 + e) * DDIM + n]);
  int nt = n >> 8, nn = n & 255;
  size_t off = ((size_t)(nt * 128 + kt) << 15) + ((size_t)kg << 12) + ((size_t)nn << 4);
  *(uint4*)(bws + off) = u.q;
}

// ---------------- kernel 3: GEMM ----------------
// BM=64 BN=256 BK=64, 512 threads = 8 waves (2M x 4N), wave tile 32x64.
// LDS: B0,B1 = 32KB each; A0,A1 = 8KB each ([kg=8][m=64][e=8] bf16); rdeg 256B.
__global__ __launch_bounds__(512) void gemm_kernel(const float* __restrict__ inc,
                                                   const unsigned char* __restrict__ bws,
                                                   const float* __restrict__ invs,
                                                   const float* __restrict__ rdeg,
                                                   float* __restrict__ out) {
  __shared__ __align__(16) unsigned char smem[82176];
  unsigned char* bBuf0 = smem;
  unsigned char* bBuf1 = smem + 32768;
  unsigned char* aBuf0 = smem + 65536;
  unsigned char* aBuf1 = smem + 73728;
  float* rdegS = (float*)(smem + 81920);

  int tid = threadIdx.x;
  int lane = tid & 63;
  int wv = tid >> 6;
  int nt = blockIdx.x;  // 0..1   (x fastest -> nt on even/odd XCDs: B stays L2-resident)
  int mt = blockIdx.y;  // 0..127
  int brow = mt * 64;
  int bcol = nt * 256;
  int wr = wv >> 2, wc = wv & 3;

  if (tid < 64) rdegS[tid] = rdeg[brow + tid];

  // A staging assignment: 2 float4 per thread per K-step
  const float4* gA[2];
  float invrA[2];
  int aWrOff[2];
#pragma unroll
  for (int i = 0; i < 2; ++i) {
    int f = i * 512 + tid;
    int sm = f >> 4, slot = f & 15;  // row-in-tile, float4-slot (k = slot*4..+3)
    gA[i] = (const float4*)(inc + (size_t)(brow + sm) * NROWS) + slot;
    invrA[i] = invs[brow + sm];
    aWrOff[i] = ((slot >> 1) << 10) + (sm << 4) + ((slot & 1) << 3);
  }

  const unsigned char* gB = bws + ((size_t)(nt * 128) << 15);
  int gOffLane = (wv << 10) + (lane << 4);
  int ldsWave = (wv << 10);

  // frag LDS byte offsets
  int aOff[2][2], bOff[2][4];
#pragma unroll
  for (int kh = 0; kh < 2; ++kh) {
    int kg = kh * 4 + (lane >> 4);
#pragma unroll
    for (int g = 0; g < 2; ++g)
      aOff[kh][g] = (kg << 10) + ((wr * 32 + g * 16 + (lane & 15)) << 4);
#pragma unroll
    for (int g = 0; g < 4; ++g)
      bOff[kh][g] = (kg << 12) + ((wc * 64 + g * 16 + (lane & 15)) << 4);
  }

  f32x4 acc[2][4];
#pragma unroll
  for (int a = 0; a < 2; ++a)
#pragma unroll
    for (int b = 0; b < 4; ++b)
      acc[a][b] = (f32x4){0.f, 0.f, 0.f, 0.f};

  // ---- prologue: stage tile 0 into buffer 0 ----
  float4 rA0 = gA[0][0];
  float4 rA1 = gA[1][0];
#pragma unroll
  for (int s = 0; s < 4; ++s) {
    __builtin_amdgcn_global_load_lds(
        (const __attribute__((address_space(1))) unsigned int*)(gB + (s << 13) + gOffLane),
        (__attribute__((address_space(3))) unsigned int*)(bBuf0 + (s << 13) + ldsWave),
        16, 0, 0);
  }
  {
    float ir0 = invrA[0], ir1 = invrA[1];
    unsigned long long pk0 =
        (unsigned long long)f2bf(rA0.x + (rA0.x > 0.f ? ir0 : 0.f)) |
        ((unsigned long long)f2bf(rA0.y + (rA0.y > 0.f ? ir0 : 0.f)) << 16) |
        ((unsigned long long)f2bf(rA0.z + (rA0.z > 0.f ? ir0 : 0.f)) << 32) |
        ((unsigned long long)f2bf(rA0.w + (rA0.w > 0.f ? ir0 : 0.f)) << 48);
    unsigned long long pk1 =
        (unsigned long long)f2bf(rA1.x + (rA1.x > 0.f ? ir1 : 0.f)) |
        ((unsigned long long)f2bf(rA1.y + (rA1.y > 0.f ? ir1 : 0.f)) << 16) |
        ((unsigned long long)f2bf(rA1.z + (rA1.z > 0.f ? ir1 : 0.f)) << 32) |
        ((unsigned long long)f2bf(rA1.w + (rA1.w > 0.f ? ir1 : 0.f)) << 48);
    *(unsigned long long*)(aBuf0 + aWrOff[0]) = pk0;
    *(unsigned long long*)(aBuf0 + aWrOff[1]) = pk1;
  }
  __syncthreads();

  unsigned char* bCur = bBuf0;
  unsigned char* bNxt = bBuf1;
  unsigned char* aCur = aBuf0;
  unsigned char* aNxt = aBuf1;

  for (int kt = 0; kt < 128; ++kt) {
    bool has_next = (kt < 127);
    float4 rN0, rN1;
    if (has_next) {
      // issue next-tile loads early (latency hides under MFMA)
      rN0 = gA[0][(kt + 1) * 16];
      rN1 = gA[1][(kt + 1) * 16];
      const unsigned char* gBk = gB + ((size_t)(kt + 1) << 15);
#pragma unroll
      for (int s = 0; s < 4; ++s) {
        __builtin_amdgcn_global_load_lds(
            (const __attribute__((address_space(1))) unsigned int*)(gBk + (s << 13) + gOffLane),
            (__attribute__((address_space(3))) unsigned int*)(bNxt + (s << 13) + ldsWave),
            16, 0, 0);
      }
    }
    // ---- compute current tile: 16 MFMA / wave ----
#pragma unroll
    for (int kh = 0; kh < 2; ++kh) {
      s16x8 af[2], bfr[4];
#pragma unroll
      for (int g = 0; g < 2; ++g) af[g] = *(const s16x8*)(aCur + aOff[kh][g]);
#pragma unroll
      for (int g = 0; g < 4; ++g) bfr[g] = *(const s16x8*)(bCur + bOff[kh][g]);
#pragma unroll
      for (int rg = 0; rg < 2; ++rg)
#pragma unroll
        for (int cg = 0; cg < 4; ++cg)
          acc[rg][cg] = __builtin_amdgcn_mfma_f32_16x16x32_bf16(af[rg], bfr[cg],
                                                                acc[rg][cg], 0, 0, 0);
    }
    // ---- write next A tile (data arrived during MFMA) ----
    if (has_next) {
      float ir0 = invrA[0], ir1 = invrA[1];
      unsigned long long pk0 =
          (unsigned long long)f2bf(rN0.x + (rN0.x > 0.f ? ir0 : 0.f)) |
          ((unsigned long long)f2bf(rN0.y + (rN0.y > 0.f ? ir0 : 0.f)) << 16) |
          ((unsigned long long)f2bf(rN0.z + (rN0.z > 0.f ? ir0 : 0.f)) << 32) |
          ((unsigned long long)f2bf(rN0.w + (rN0.w > 0.f ? ir0 : 0.f)) << 48);
      unsigned long long pk1 =
          (unsigned long long)f2bf(rN1.x + (rN1.x > 0.f ? ir1 : 0.f)) |
          ((unsigned long long)f2bf(rN1.y + (rN1.y > 0.f ? ir1 : 0.f)) << 16) |
          ((unsigned long long)f2bf(rN1.z + (rN1.z > 0.f ? ir1 : 0.f)) << 32) |
          ((unsigned long long)f2bf(rN1.w + (rN1.w > 0.f ? ir1 : 0.f)) << 48);
      *(unsigned long long*)(aNxt + aWrOff[0]) = pk0;
      *(unsigned long long*)(aNxt + aWrOff[1]) = pk1;
    }
    __syncthreads();  // drains vmcnt (B lds-loads) + lgkm (A writes)
    unsigned char* t;
    t = bCur; bCur = bNxt; bNxt = t;
    t = aCur; aCur = aNxt; aNxt = t;
  }

  // ---- epilogue: * rdeg, store fp32 ----
#pragma unroll
  for (int rg = 0; rg < 2; ++rg) {
    int rb = wr * 32 + rg * 16 + ((lane >> 4) << 2);
#pragma unroll
    for (int cg = 0; cg < 4; ++cg) {
      int col = bcol + wc * 64 + cg * 16 + (lane & 15);
#pragma unroll
      for (int r = 0; r < 4; ++r) {
        int rl = rb + r;
        out[(size_t)(brow + rl) * DDIM + col] = acc[rg][cg][r] * rdegS[rl];
      }
    }
  }
}

extern "C" void kernel_launch(void* const* d_in, const int* in_sizes, int n_in,
                              void* d_out, int out_size, void* d_ws, size_t ws_size,
                              hipStream_t stream) {
  const float* cur = (const float*)d_in[0];          // [8192, 512] fp32
  const float* incm = (const float*)d_in[1];         // [8192, 8192] fp32
  float* out = (float*)d_out;                        // [8192, 512] fp32
  unsigned char* ws = (unsigned char*)d_ws;
  float* invs = (float*)ws;                          // 32KB
  float* rdeg = (float*)(ws + 32768);                // 32KB
  unsigned char* bws = ws + 65536;                   // 8MB B chunks

  hipLaunchKernelGGL(stats_kernel, dim3(NROWS), dim3(256), 0, stream, incm, invs, rdeg);
  hipLaunchKernelGGL(bprep_kernel, dim3((NROWS / 64) * 8 * DDIM / 256), dim3(256), 0, stream,
                     cur, bws);
  hipLaunchKernelGGL(gemm_kernel, dim3(2, 128), dim3(512), 0, stream, incm, bws, invs, rdeg, out);
}

// Round 3
// 182.136 us; speedup vs baseline: 1.5746x; 1.1148x over previous
//
#include <hip/hip_runtime.h>
#include <stdint.h>

// SpatialHyperedgeMP: out = ((inc + head) @ cur) / rowsum(inc + head)
//   head_ij = (inc_ij > 0) / sqrt(cnt_i),  cnt_i = #positives in row i
//
// Kernels:
//   1) stats:  per-row fp64 sum + positive count -> invs[i]=1/sqrt(cnt), rdeg[i]=1/(s1+sqrt(cnt))
//   2) bprep:  cur fp32 -> bf16, transposed into MFMA-chunk layout in ws
//   3) gemm:   bf16 MFMA 16x16x32, BM=64 BN=256 BK=64, 512 thr (8 waves),
//              deep pipeline: raw s_barrier + counted vmcnt (T3/T4), A-regs
//              prefetched 2 tiles ahead, XOR-swizzled A LDS (conflict-free
//              b128 write+read), setprio around MFMA (T5).
//
// ws usage: 32KB invs + 32KB rdeg + 8MB B chunks.

#define NROWS 8192
#define DDIM  512

typedef float f32x4 __attribute__((ext_vector_type(4)));
typedef short s16x8 __attribute__((ext_vector_type(8)));

__device__ __forceinline__ unsigned short f2bf(float f) {
  union { float f; unsigned int u; } c; c.f = f;
  unsigned int u = c.u;
  unsigned int r = u + 0x7FFFu + ((u >> 16) & 1u);
  return (unsigned short)(r >> 16);
}

// ---------------- kernel 1: row stats ----------------
__global__ __launch_bounds__(256) void stats_kernel(const float* __restrict__ inc,
                                                    float* __restrict__ invs,
                                                    float* __restrict__ rdeg) {
  int row = blockIdx.x;
  int tid = threadIdx.x;
  const float4* p = (const float4*)(inc + (size_t)row * NROWS);
  double s = 0.0;
  int c = 0;
#pragma unroll
  for (int i = 0; i < 8; ++i) {
    float4 v = p[i * 256 + tid];
    s += (double)v.x + (double)v.y + (double)v.z + (double)v.w;
    c += (v.x > 0.f) + (v.y > 0.f) + (v.z > 0.f) + (v.w > 0.f);
  }
  for (int off = 32; off > 0; off >>= 1) {
    s += __shfl_down(s, off);
    c += __shfl_down(c, off);
  }
  __shared__ double sw[4];
  __shared__ int cw[4];
  int lane = tid & 63, wv = tid >> 6;
  if (lane == 0) { sw[wv] = s; cw[wv] = c; }
  __syncthreads();
  if (tid == 0) {
    double S = sw[0] + sw[1] + sw[2] + sw[3];
    int C = cw[0] + cw[1] + cw[2] + cw[3];
    double sq = sqrt((double)C);
    invs[row] = (C > 0) ? (float)(1.0 / sq) : 0.0f;
    rdeg[row] = (float)(1.0 / (S + sq));
  }
}

// ---------------- kernel 2: B prep (cur -> bf16 chunked-transposed) ----------------
// chunk layout: for nt(2) x kt(128): 32KB chunk = [kg=8][nn=256][e=8] bf16
__global__ __launch_bounds__(256) void bprep_kernel(const float* __restrict__ cur,
                                                    unsigned char* __restrict__ bws) {
  int idx = blockIdx.x * 256 + threadIdx.x;  // 0..524287
  int n = idx & 511;
  int kg9 = idx >> 9;  // 0..1023
  int kt = kg9 >> 3;
  int kg = kg9 & 7;
  int k0 = kt * 64 + kg * 8;
  union { unsigned short h[8]; uint4 q; } u;
#pragma unroll
  for (int e = 0; e < 8; ++e)
    u.h[e] = f2bf(cur[(size_t)(k0 + e) * DDIM + n]);
  int nt = n >> 8, nn = n & 255;
  size_t off = ((size_t)(nt * 128 + kt) << 15) + ((size_t)kg << 12) + ((size_t)nn << 4);
  *(uint4*)(bws + off) = u.q;
}

// ---------------- kernel 3: GEMM ----------------
// BM=64 BN=256 BK=64, 512 threads = 8 waves (2M x 4N), wave tile 32x64.
// LDS: B0,B1 = 32KB; A0,A1 = 8KB ([kg=8][slot=64][e=8] bf16, slot = row^kg); rdeg 256B.
// Pipeline invariant entering tile kt: per-wave vmem FIFO = [A(kt+1):2, B(kt+1):4].

#define FENCE() __builtin_amdgcn_sched_barrier(0)
#define BARRIER() __builtin_amdgcn_s_barrier()
#define WAITVM2() asm volatile("s_waitcnt vmcnt(2) lgkmcnt(0)" ::: "memory")
#define WAITVM0() asm volatile("s_waitcnt vmcnt(0) lgkmcnt(0)" ::: "memory")

__global__ __launch_bounds__(512) void gemm_kernel(const float* __restrict__ inc,
                                                   const unsigned char* __restrict__ bws,
                                                   const float* __restrict__ invs,
                                                   const float* __restrict__ rdeg,
                                                   float* __restrict__ out) {
  __shared__ __align__(16) unsigned char smem[82176];
  unsigned char* const bBuf0 = smem;
  unsigned char* const bBuf1 = smem + 32768;
  unsigned char* const aBuf0 = smem + 65536;
  unsigned char* const aBuf1 = smem + 73728;
  float* const rdegS = (float*)(smem + 81920);

  const int tid = threadIdx.x;
  const int lane = tid & 63;
  const int wv = tid >> 6;
  const int nt = blockIdx.x;  // 0..1
  const int mt = blockIdx.y;  // 0..127
  const int brow = mt * 64;
  const int bcol = nt * 256;
  const int wr = wv >> 2, wc = wv & 3;

  if (tid < 64) rdegS[tid] = rdeg[brow + tid];

  // A ownership: thread -> (row sm, k-octet sp); one b128 LDS write per tile.
  const int sm = tid >> 3;   // 0..63
  const int sp = tid & 7;    // 0..7
  const float4* gAr = (const float4*)(inc + (size_t)(brow + sm) * NROWS) + sp * 2;
  const float invr = invs[brow + sm];
  const int aWr = (sp << 10) + ((sm ^ sp) << 4);  // XOR swizzle (low 3 bits of row)

  const unsigned char* gB = bws + ((size_t)(nt * 128) << 15);
  const int gOffLane = (wv << 10) + (lane << 4);
  const int ldsWave = (wv << 10);

  // fragment LDS byte offsets
  int aOff[2][2], bOff[2][4];
#pragma unroll
  for (int kh = 0; kh < 2; ++kh) {
    int kg = kh * 4 + (lane >> 4);
#pragma unroll
    for (int g = 0; g < 2; ++g) {
      int r = wr * 32 + g * 16 + (lane & 15);
      aOff[kh][g] = (kg << 10) + ((r ^ kg) << 4);  // matching read-side swizzle
    }
#pragma unroll
    for (int g = 0; g < 4; ++g)
      bOff[kh][g] = (kg << 12) + ((wc * 64 + g * 16 + (lane & 15)) << 4);
  }

  f32x4 acc[2][4];
#pragma unroll
  for (int a = 0; a < 2; ++a)
#pragma unroll
    for (int b = 0; b < 4; ++b)
      acc[a][b] = (f32x4){0.f, 0.f, 0.f, 0.f};

  float4 x0, x1, y0, y1;

#define ISSUE_A(d0, d1, KT) do { d0 = gAr[(KT) * 16]; d1 = gAr[(KT) * 16 + 1]; } while (0)

#define ISSUE_B(KT, BDST) do {                                                            \
    const unsigned char* _g = gB + ((size_t)(KT) << 15);                                  \
    _Pragma("unroll")                                                                     \
    for (int _s = 0; _s < 4; ++_s)                                                        \
      __builtin_amdgcn_global_load_lds(                                                   \
          (const __attribute__((address_space(1))) unsigned int*)(_g + (_s << 13) + gOffLane), \
          (__attribute__((address_space(3))) unsigned int*)((BDST) + (_s << 13) + ldsWave),    \
          16, 0, 0);                                                                      \
  } while (0)

#define XFORM(s0, s1, ADST) do {                                                          \
    uint4 _w;                                                                             \
    _w.x = (unsigned int)f2bf(s0.x + (s0.x > 0.f ? invr : 0.f)) |                         \
           ((unsigned int)f2bf(s0.y + (s0.y > 0.f ? invr : 0.f)) << 16);                  \
    _w.y = (unsigned int)f2bf(s0.z + (s0.z > 0.f ? invr : 0.f)) |                         \
           ((unsigned int)f2bf(s0.w + (s0.w > 0.f ? invr : 0.f)) << 16);                  \
    _w.z = (unsigned int)f2bf(s1.x + (s1.x > 0.f ? invr : 0.f)) |                         \
           ((unsigned int)f2bf(s1.y + (s1.y > 0.f ? invr : 0.f)) << 16);                  \
    _w.w = (unsigned int)f2bf(s1.z + (s1.z > 0.f ? invr : 0.f)) |                         \
           ((unsigned int)f2bf(s1.w + (s1.w > 0.f ? invr : 0.f)) << 16);                  \
    *(uint4*)((ADST) + aWr) = _w;                                                         \
  } while (0)

#define MFMA_TILE(AC, BC) do {                                                            \
    __builtin_amdgcn_s_setprio(1);                                                        \
    _Pragma("unroll")                                                                     \
    for (int kh = 0; kh < 2; ++kh) {                                                      \
      s16x8 af[2], bfr[4];                                                                \
      _Pragma("unroll")                                                                   \
      for (int g = 0; g < 2; ++g) af[g] = *(const s16x8*)((AC) + aOff[kh][g]);            \
      _Pragma("unroll")                                                                   \
      for (int g = 0; g < 4; ++g) bfr[g] = *(const s16x8*)((BC) + bOff[kh][g]);           \
      _Pragma("unroll")                                                                   \
      for (int rg = 0; rg < 2; ++rg)                                                      \
        _Pragma("unroll")                                                                 \
        for (int cg = 0; cg < 4; ++cg)                                                    \
          acc[rg][cg] = __builtin_amdgcn_mfma_f32_16x16x32_bf16(af[rg], bfr[cg],          \
                                                                acc[rg][cg], 0, 0, 0);   \
    }                                                                                     \
    __builtin_amdgcn_s_setprio(0);                                                        \
  } while (0)

  // ---- prologue: queue -> [A(1):2, B(1):4] with buf0 ready ----
  ISSUE_A(x0, x1, 0);
  ISSUE_B(0, bBuf0);
  ISSUE_A(y0, y1, 1);
  XFORM(x0, x1, aBuf0);  // compiler auto-waits A(0) regs precisely
  FENCE();
  WAITVM2();             // retire B(0) (+rdeg on wave 0); leave A(1) in flight
  FENCE();
  BARRIER();
  FENCE();
  ISSUE_B(1, bBuf1);

  // ---- steady: tiles 0..125, unrolled by 2 for static reg/buffer names ----
  for (int kt = 0; kt < 126; kt += 2) {
    // even tile kt: compute(a0,b0); pending y=A(kt+1)
    ISSUE_A(x0, x1, kt + 2);
    MFMA_TILE(aBuf0, bBuf0);
    XFORM(y0, y1, aBuf1);
    FENCE();
    WAITVM2();           // retire B(kt+1); leave A(kt+2)
    FENCE();
    BARRIER();
    FENCE();
    ISSUE_B(kt + 2, bBuf0);
    // odd tile kt+1: compute(a1,b1); pending x=A(kt+2)
    ISSUE_A(y0, y1, kt + 3);
    MFMA_TILE(aBuf1, bBuf1);
    XFORM(x0, x1, aBuf0);
    FENCE();
    WAITVM2();           // retire B(kt+2); leave A(kt+3)
    FENCE();
    BARRIER();
    FENCE();
    ISSUE_B(kt + 3, bBuf1);
  }

  // ---- tail: tile 126 ----
  MFMA_TILE(aBuf0, bBuf0);
  XFORM(y0, y1, aBuf1);  // A(127)
  FENCE();
  WAITVM0();             // drain B(127); nothing else outstanding
  FENCE();
  BARRIER();
  FENCE();
  // ---- tail: tile 127 ----
  MFMA_TILE(aBuf1, bBuf1);

  // ---- epilogue: * rdeg, store fp32 ----
#pragma unroll
  for (int rg = 0; rg < 2; ++rg) {
    int rb = wr * 32 + rg * 16 + ((lane >> 4) << 2);
#pragma unroll
    for (int cg = 0; cg < 4; ++cg) {
      int col = bcol + wc * 64 + cg * 16 + (lane & 15);
#pragma unroll
      for (int r = 0; r < 4; ++r) {
        int rl = rb + r;
        out[(size_t)(brow + rl) * DDIM + col] = acc[rg][cg][r] * rdegS[rl];
      }
    }
  }
#undef ISSUE_A
#undef ISSUE_B
#undef XFORM
#undef MFMA_TILE
}

extern "C" void kernel_launch(void* const* d_in, const int* in_sizes, int n_in,
                              void* d_out, int out_size, void* d_ws, size_t ws_size,
                              hipStream_t stream) {
  const float* cur = (const float*)d_in[0];          // [8192, 512] fp32
  const float* incm = (const float*)d_in[1];         // [8192, 8192] fp32
  float* out = (float*)d_out;                        // [8192, 512] fp32
  unsigned char* ws = (unsigned char*)d_ws;
  float* invs = (float*)ws;                          // 32KB
  float* rdeg = (float*)(ws + 32768);                // 32KB
  unsigned char* bws = ws + 65536;                   // 8MB B chunks

  hipLaunchKernelGGL(stats_kernel, dim3(NROWS), dim3(256), 0, stream, incm, invs, rdeg);
  hipLaunchKernelGGL(bprep_kernel, dim3((NROWS / 64) * 8 * DDIM / 256), dim3(256), 0, stream,
                     cur, bws);
  hipLaunchKernelGGL(gemm_kernel, dim3(2, 128), dim3(512), 0, stream, incm, bws, invs, rdeg, out);
}